// Round 1
// baseline (68.953 us; speedup 1.0000x reference)
//
#include <hip/hip_runtime.h>
#include <math.h>
#include <float.h>

#define B_ 2
#define NQ 1024
#define NO 1024
#define LAT 128
#define NHEADS 4
#define RADIUS_ 0.5f
#define LN_EPS_ 1e-5f

// ---------------- prep: v = LayerNorm(h_obs) @ Wv + bv ----------------
// grid: B_*NO blocks, 128 threads. v layout: (B, No, 128) fp32 in workspace.
__global__ __launch_bounds__(128) void gano_prep_kernel(
    const float* __restrict__ h_obs, const float* __restrict__ ln_g,
    const float* __restrict__ ln_b, const float* __restrict__ Wv,
    const float* __restrict__ bv, float* __restrict__ v_out)
{
  const int r = blockIdx.x;           // b*NO + o
  const int j = threadIdx.x;          // 0..127
  __shared__ float s_red[2];
  __shared__ float s_hn[LAT];

  const float x = h_obs[(size_t)r * LAT + j];

  // block sum over 128 threads (2 waves)
  float s = x;
  #pragma unroll
  for (int off = 32; off >= 1; off >>= 1) s += __shfl_down(s, off);
  if ((j & 63) == 0) s_red[j >> 6] = s;
  __syncthreads();
  const float mu = (s_red[0] + s_red[1]) * (1.0f / LAT);
  const float d = x - mu;
  __syncthreads();
  float s2 = d * d;
  #pragma unroll
  for (int off = 32; off >= 1; off >>= 1) s2 += __shfl_down(s2, off);
  if ((j & 63) == 0) s_red[j >> 6] = s2;
  __syncthreads();
  const float var = (s_red[0] + s_red[1]) * (1.0f / LAT);
  const float rstd = rsqrtf(var + LN_EPS_);
  s_hn[j] = d * rstd * ln_g[j] + ln_b[j];
  __syncthreads();

  float acc = bv[j];
  #pragma unroll 4
  for (int k = 0; k < LAT; ++k)
    acc = fmaf(s_hn[k], Wv[k * LAT + j], acc);
  v_out[(size_t)r * LAT + j] = acc;
}

// ---------------- main: per-query compact + MLP logits + softmax + PV ----
// grid: B_*NQ blocks, 256 threads. One block = one (b, q).
__global__ __launch_bounds__(256) void gano_main_kernel(
    const float* __restrict__ pos_obs, const float* __restrict__ pos_query,
    const int* __restrict__ obs_mask,
    const float* __restrict__ W1, const float* __restrict__ b1,
    const float* __restrict__ W2, const float* __restrict__ b2,
    const float* __restrict__ v, float* __restrict__ out)
{
  __shared__ float s_opos[3][NO];      // 12 KB
  __shared__ int   s_vidx[NO];         // 4 KB
  __shared__ float s_vdist[NO];        // 4 KB
  __shared__ float s_p[NHEADS][NO];    // 16 KB: logits then p=exp(l-m)
  __shared__ float s_wrow[LAT][8];     // 4 KB: C0,C1,C2,w9,W2[j][0..3]
  __shared__ float s_Q[LAT];           // 512 B
  __shared__ float s_red[4][NHEADS];   // per-wave reduction partials
  __shared__ int   s_wcnt[4];
  __shared__ int   s_base;
  __shared__ float s_mz[2][NHEADS];    // [0]=max, [1]=1/Z
  __shared__ float s_acc[LAT];

  const int tid = threadIdx.x;
  const int bid = blockIdx.x;
  const int b = bid / NQ, q = bid - b * NQ;
  const int wave = tid >> 6, lane = tid & 63;

  const float qx = pos_query[((size_t)b * NQ + q) * 3 + 0];
  const float qy = pos_query[((size_t)b * NQ + q) * 3 + 1];
  const float qz = pos_query[((size_t)b * NQ + q) * 3 + 2];

  // stage pos_obs for this batch, transposed
  for (int i = tid; i < NO * 3; i += 256) {
    const float val = pos_obs[(size_t)b * NO * 3 + i];
    s_opos[i % 3][i / 3] = val;
  }
  // per-j constant rows + per-query Q row
  if (tid < LAT) {
    const int j = tid;
    float w[10];
    #pragma unroll
    for (int k = 0; k < 10; ++k) w[k] = W1[k * LAT + j];
    s_wrow[j][0] = w[3] - w[6];
    s_wrow[j][1] = w[4] - w[7];
    s_wrow[j][2] = w[5] - w[8];
    s_wrow[j][3] = w[9];
    #pragma unroll
    for (int h = 0; h < NHEADS; ++h) s_wrow[j][4 + h] = W2[j * NHEADS + h];
    s_Q[j] = b1[j] + qx * (w[0] + w[6]) + qy * (w[1] + w[7]) + qz * (w[2] + w[8]);
  }
  if (tid == 0) s_base = 0;
  __syncthreads();

  // deterministic compaction of valid obs (4 rounds of 256)
  for (int rd = 0; rd < NO / 256; ++rd) {
    const int o = rd * 256 + tid;
    const float rx = qx - s_opos[0][o];
    const float ry = qy - s_opos[1][o];
    const float rz = qz - s_opos[2][o];
    const float dist = sqrtf(rx * rx + ry * ry + rz * rz);
    const int ok = (obs_mask[(size_t)b * NO + o] != 0) && !(dist > RADIUS_);
    const unsigned long long bal = __ballot(ok);
    if (lane == 0) s_wcnt[wave] = __popcll(bal);
    __syncthreads();
    int base = s_base;
    for (int w2 = 0; w2 < wave; ++w2) base += s_wcnt[w2];
    if (ok) {
      const int pos = base + __popcll(bal & ((1ull << lane) - 1ull));
      s_vidx[pos] = o;
      s_vdist[pos] = dist;
    }
    __syncthreads();
    if (tid == 0) s_base += s_wcnt[0] + s_wcnt[1] + s_wcnt[2] + s_wcnt[3];
    __syncthreads();
  }
  const int Nv = s_base;

  // MLP: logits for valid obs
  const float b20 = b2[0], b21 = b2[1], b22 = b2[2], b23 = b2[3];
  for (int t = tid; t < Nv; t += 256) {
    const int o = s_vidx[t];
    const float dist = s_vdist[t];
    const float ox = s_opos[0][o], oy = s_opos[1][o], oz = s_opos[2][o];
    float l0 = b20, l1 = b21, l2 = b22, l3 = b23;
    #pragma unroll 2
    for (int j = 0; j < LAT; ++j) {
      const float4 c = *(const float4*)&s_wrow[j][0];
      const float4 w = *(const float4*)&s_wrow[j][4];
      float t0 = fmaf(c.x, ox, s_Q[j]);
      t0 = fmaf(c.y, oy, t0);
      t0 = fmaf(c.z, oz, t0);
      t0 = fmaf(c.w, dist, t0);
      const float hd = fmaxf(t0, 0.0f);
      l0 = fmaf(hd, w.x, l0);
      l1 = fmaf(hd, w.y, l1);
      l2 = fmaf(hd, w.z, l2);
      l3 = fmaf(hd, w.w, l3);
    }
    s_p[0][t] = l0; s_p[1][t] = l1; s_p[2][t] = l2; s_p[3][t] = l3;
  }
  __syncthreads();

  // softmax: per-head max
  float mx[NHEADS] = {-FLT_MAX, -FLT_MAX, -FLT_MAX, -FLT_MAX};
  for (int t = tid; t < Nv; t += 256) {
    #pragma unroll
    for (int h = 0; h < NHEADS; ++h) mx[h] = fmaxf(mx[h], s_p[h][t]);
  }
  #pragma unroll
  for (int h = 0; h < NHEADS; ++h) {
    float m = mx[h];
    #pragma unroll
    for (int off = 32; off >= 1; off >>= 1) m = fmaxf(m, __shfl_down(m, off));
    if (lane == 0) s_red[wave][h] = m;
  }
  __syncthreads();
  if (tid == 0) {
    #pragma unroll
    for (int h = 0; h < NHEADS; ++h)
      s_mz[0][h] = fmaxf(fmaxf(s_red[0][h], s_red[1][h]),
                         fmaxf(s_red[2][h], s_red[3][h]));
  }
  __syncthreads();

  // p = exp(l - m), accumulate Z
  float sm[NHEADS] = {0.f, 0.f, 0.f, 0.f};
  const float m0 = s_mz[0][0], m1 = s_mz[0][1], m2 = s_mz[0][2], m3 = s_mz[0][3];
  for (int t = tid; t < Nv; t += 256) {
    float e0 = __expf(s_p[0][t] - m0);
    float e1 = __expf(s_p[1][t] - m1);
    float e2 = __expf(s_p[2][t] - m2);
    float e3 = __expf(s_p[3][t] - m3);
    s_p[0][t] = e0; s_p[1][t] = e1; s_p[2][t] = e2; s_p[3][t] = e3;
    sm[0] += e0; sm[1] += e1; sm[2] += e2; sm[3] += e3;
  }
  #pragma unroll
  for (int h = 0; h < NHEADS; ++h) {
    float s = sm[h];
    #pragma unroll
    for (int off = 32; off >= 1; off >>= 1) s += __shfl_down(s, off);
    if (lane == 0) s_red[wave][h] = s;
  }
  __syncthreads();
  if (tid == 0) {
    #pragma unroll
    for (int h = 0; h < NHEADS; ++h) {
      const float Z = s_red[0][h] + s_red[1][h] + s_red[2][h] + s_red[3][h];
      s_mz[1][h] = 1.0f / Z;
    }
  }
  __syncthreads();

  // PV: out[col] = (sum_t p[h][t] * v[o_t][col]) / Z_h
  const int col = tid & 127;
  const int half = tid >> 7;
  const int h = col >> 5;
  const float rZ = s_mz[1][h];
  float acc = 0.0f;
  const float* vb = v + (size_t)b * NO * LAT;
  #pragma unroll 4
  for (int t = half; t < Nv; t += 2)
    acc = fmaf(s_p[h][t], vb[(size_t)s_vidx[t] * LAT + col], acc);
  if (half) s_acc[col] = acc;
  __syncthreads();
  if (!half) {
    float r = (acc + s_acc[col]) * rZ;
    if (Nv == 0) r = 0.0f;
    out[((size_t)b * NQ + q) * LAT + col] = r;
  }
}

extern "C" void kernel_launch(void* const* d_in, const int* in_sizes, int n_in,
                              void* d_out, int out_size, void* d_ws, size_t ws_size,
                              hipStream_t stream) {
  const float* h_obs     = (const float*)d_in[0];
  const float* pos_obs   = (const float*)d_in[1];
  const float* pos_query = (const float*)d_in[2];
  const int*   obs_mask  = (const int*)d_in[3];
  const float* W1        = (const float*)d_in[4];
  const float* b1        = (const float*)d_in[5];
  const float* W2        = (const float*)d_in[6];
  const float* b2        = (const float*)d_in[7];
  const float* ln_g      = (const float*)d_in[8];
  const float* ln_b      = (const float*)d_in[9];
  const float* Wv        = (const float*)d_in[10];
  const float* bv        = (const float*)d_in[11];
  float* outp = (float*)d_out;
  float* v    = (float*)d_ws;   // B*NO*LAT floats = 1 MB

  gano_prep_kernel<<<B_ * NO, 128, 0, stream>>>(h_obs, ln_g, ln_b, Wv, bv, v);
  gano_main_kernel<<<B_ * NQ, 256, 0, stream>>>(pos_obs, pos_query, obs_mask,
                                                W1, b1, W2, b2, v, outp);
}

// Round 2
// 48.186 us; speedup vs baseline: 1.4310x; 1.4310x over previous
//
#include <hip/hip_runtime.h>
#include <math.h>
#include <float.h>

#define B_ 2
#define NQ 1024
#define NO 1024
#define LAT 128
#define NHEADS 4
#define RADIUS_ 0.5f
#define LN_EPS_ 1e-5f

// workspace layout (bytes):
//   [0, B_*NO*LAT*4)          v  (B,No,128) fp32
//   then LAT*16               Cw[j] = (W1[3]-W1[6], W1[4]-W1[7], W1[5]-W1[8], W1[9]) col j
//   then LAT*16               A4[j] = (W1[0]+W1[6], W1[1]+W1[7], W1[2]+W1[8], b1) col j
#define V_BYTES ((size_t)B_ * NO * LAT * 4)

// ---------------- prep: v = LayerNorm(h_obs) @ Wv + bv (+ derived weights) --
__global__ __launch_bounds__(128) void gano_prep_kernel(
    const float* __restrict__ h_obs, const float* __restrict__ ln_g,
    const float* __restrict__ ln_b, const float* __restrict__ Wv,
    const float* __restrict__ bv, const float* __restrict__ W1,
    const float* __restrict__ b1, float* __restrict__ v_out,
    float4* __restrict__ Cw, float4* __restrict__ A4, int write_derived)
{
  const int r = blockIdx.x;           // b*NO + o
  const int j = threadIdx.x;          // 0..127
  __shared__ float s_red[2];
  __shared__ __align__(16) float s_hn[LAT];

  const float x = h_obs[(size_t)r * LAT + j];

  float s = x;
  #pragma unroll
  for (int off = 32; off >= 1; off >>= 1) s += __shfl_down(s, off);
  if ((j & 63) == 0) s_red[j >> 6] = s;
  __syncthreads();
  const float mu = (s_red[0] + s_red[1]) * (1.0f / LAT);
  const float d = x - mu;
  __syncthreads();
  float s2 = d * d;
  #pragma unroll
  for (int off = 32; off >= 1; off >>= 1) s2 += __shfl_down(s2, off);
  if ((j & 63) == 0) s_red[j >> 6] = s2;
  __syncthreads();
  const float var = (s_red[0] + s_red[1]) * (1.0f / LAT);
  const float rstd = rsqrtf(var + LN_EPS_);
  s_hn[j] = d * rstd * ln_g[j] + ln_b[j];
  __syncthreads();

  float acc = bv[j];
  const float4* hn4 = (const float4*)s_hn;
  #pragma unroll 4
  for (int k4 = 0; k4 < LAT / 4; ++k4) {
    const float4 h4 = hn4[k4];
    acc = fmaf(h4.x, Wv[(k4 * 4 + 0) * LAT + j], acc);
    acc = fmaf(h4.y, Wv[(k4 * 4 + 1) * LAT + j], acc);
    acc = fmaf(h4.z, Wv[(k4 * 4 + 2) * LAT + j], acc);
    acc = fmaf(h4.w, Wv[(k4 * 4 + 3) * LAT + j], acc);
  }
  v_out[(size_t)r * LAT + j] = acc;

  if (write_derived && r == 0) {
    float w[10];
    #pragma unroll
    for (int k = 0; k < 10; ++k) w[k] = W1[k * LAT + j];
    Cw[j] = make_float4(w[3] - w[6], w[4] - w[7], w[5] - w[8], w[9]);
    A4[j] = make_float4(w[0] + w[6], w[1] + w[7], w[2] + w[8], b1[j]);
  }
}

// ---------------- main: one block = one (b,q), 256 threads -----------------
template <bool DERIVED>
__global__ __launch_bounds__(256, 8) void gano_main_kernel(
    const float* __restrict__ pos_obs, const float* __restrict__ pos_query,
    const int* __restrict__ obs_mask,
    const float* __restrict__ W1, const float* __restrict__ b1,
    const float4* __restrict__ W2v, const float* __restrict__ b2,
    const float* __restrict__ v,
    const float4* __restrict__ Cw, const float4* __restrict__ A4,
    float* __restrict__ out)
{
  __shared__ __align__(16) float s_Q[LAT];   // 512 B
  __shared__ int   s_vidx[NO];               // 4 KB
  __shared__ float s_vdist[NO];              // 4 KB
  __shared__ float s_p[NHEADS][256];         // 4 KB (per tile)
  __shared__ int   s_cnt[16];
  __shared__ float s_red[NHEADS][4];
  __shared__ float s_m[NHEADS];
  __shared__ float s_z[NHEADS];
  __shared__ float s_scale[NHEADS];
  __shared__ float s_acc[LAT];               // 512 B

  const int tid = threadIdx.x;
  const int wave = tid >> 6, lane = tid & 63;
  const int bid = blockIdx.x;
  const int b = bid >> 10, q = bid & (NQ - 1);

  const float qx = pos_query[((size_t)b * NQ + q) * 3 + 0];
  const float qy = pos_query[((size_t)b * NQ + q) * 3 + 1];
  const float qz = pos_query[((size_t)b * NQ + q) * 3 + 2];

  // per-query Q row: Q[j] = b1[j] + qx*A0 + qy*A1 + qz*A2
  if (tid < LAT) {
    float a0, a1, a2, a3;
    if constexpr (DERIVED) {
      const float4 a = A4[tid];
      a0 = a.x; a1 = a.y; a2 = a.z; a3 = a.w;
    } else {
      a0 = W1[0 * LAT + tid] + W1[6 * LAT + tid];
      a1 = W1[1 * LAT + tid] + W1[7 * LAT + tid];
      a2 = W1[2 * LAT + tid] + W1[8 * LAT + tid];
      a3 = b1[tid];
    }
    s_Q[tid] = fmaf(qx, a0, fmaf(qy, a1, fmaf(qz, a2, a3)));
  }
  if (tid < NHEADS) { s_m[tid] = -FLT_MAX; s_z[tid] = 0.0f; }

  // ---- compaction of valid obs (2 syncs total) ----
  const float* pob = pos_obs + (size_t)b * NO * 3;
  const int*   om  = obs_mask + (size_t)b * NO;
  float dists[4];
  unsigned long long bals[4];
  #pragma unroll
  for (int rd = 0; rd < 4; ++rd) {
    const int o = (rd << 8) + tid;
    const float ox = pob[o * 3 + 0], oy = pob[o * 3 + 1], oz = pob[o * 3 + 2];
    const float rx = qx - ox, ry = qy - oy, rz = qz - oz;
    const float dist = sqrtf(rx * rx + ry * ry + rz * rz);
    const int ok = (om[o] != 0) && (dist <= RADIUS_);
    const unsigned long long bal = __ballot(ok);
    if (lane == 0) s_cnt[(rd << 2) + wave] = __popcll(bal);
    bals[rd] = bal;
    dists[rd] = dist;
  }
  __syncthreads();
  int Nv = 0;
  #pragma unroll
  for (int k = 0; k < 16; ++k) Nv += s_cnt[k];
  #pragma unroll
  for (int rd = 0; rd < 4; ++rd) {
    const int slot = (rd << 2) + wave;
    int base = 0;
    for (int k = 0; k < slot; ++k) base += s_cnt[k];
    if ((bals[rd] >> lane) & 1ull) {
      const int pos = base + __popcll(bals[rd] & ((1ull << lane) - 1ull));
      s_vidx[pos] = (rd << 8) + tid;
      s_vdist[pos] = dists[rd];
    }
  }
  __syncthreads();

  // ---- tiled online-softmax + PV ----
  const int col = tid & (LAT - 1);
  const int half = tid >> 7;
  const int hh = col >> 5;
  float acc = 0.0f;
  const float* vb = v + (size_t)b * NO * LAT;
  const float b20 = b2[0], b21 = b2[1], b22 = b2[2], b23 = b2[3];

  const int ntiles = (Nv + 255) >> 8;
  for (int tile = 0; tile < ntiles; ++tile) {
    const int tbase = tile << 8;
    const int t = tbase + tid;
    const bool active = t < Nv;
    float l0 = -FLT_MAX, l1 = -FLT_MAX, l2 = -FLT_MAX, l3 = -FLT_MAX;
    if (__any(active)) {
      const int tt = active ? t : (Nv - 1);
      const int idx = s_vidx[tt];
      const float dist = s_vdist[tt];
      const float ox = pob[idx * 3 + 0], oy = pob[idx * 3 + 1], oz = pob[idx * 3 + 2];
      float a0 = b20, a1 = b21, a2 = b22, a3 = b23;
      for (int j4 = 0; j4 < LAT / 4; ++j4) {
        const float4 q4 = *(const float4*)&s_Q[j4 << 2];
        #pragma unroll
        for (int u = 0; u < 4; ++u) {
          const int j = (j4 << 2) + u;
          float4 cw;
          if constexpr (DERIVED) {
            cw = Cw[j];
          } else {
            cw = make_float4(W1[3 * LAT + j] - W1[6 * LAT + j],
                             W1[4 * LAT + j] - W1[7 * LAT + j],
                             W1[5 * LAT + j] - W1[8 * LAT + j],
                             W1[9 * LAT + j]);
          }
          const float4 w2 = W2v[j];
          const float qj = (u == 0) ? q4.x : (u == 1) ? q4.y : (u == 2) ? q4.z : q4.w;
          float t0 = fmaf(cw.x, ox, qj);
          t0 = fmaf(cw.y, oy, t0);
          t0 = fmaf(cw.z, oz, t0);
          t0 = fmaf(cw.w, dist, t0);
          t0 = fmaxf(t0, 0.0f);
          a0 = fmaf(t0, w2.x, a0);
          a1 = fmaf(t0, w2.y, a1);
          a2 = fmaf(t0, w2.z, a2);
          a3 = fmaf(t0, w2.w, a3);
        }
      }
      if (active) { l0 = a0; l1 = a1; l2 = a2; l3 = a3; }
    }

    // tile max (per head)
    float m0 = l0, m1 = l1, m2 = l2, m3 = l3;
    #pragma unroll
    for (int off = 32; off >= 1; off >>= 1) {
      m0 = fmaxf(m0, __shfl_down(m0, off));
      m1 = fmaxf(m1, __shfl_down(m1, off));
      m2 = fmaxf(m2, __shfl_down(m2, off));
      m3 = fmaxf(m3, __shfl_down(m3, off));
    }
    if (lane == 0) { s_red[0][wave] = m0; s_red[1][wave] = m1;
                     s_red[2][wave] = m2; s_red[3][wave] = m3; }
    __syncthreads();
    if (tid < NHEADS) {
      const float tm = fmaxf(fmaxf(s_red[tid][0], s_red[tid][1]),
                             fmaxf(s_red[tid][2], s_red[tid][3]));
      const float om_ = s_m[tid];
      const float nm = fmaxf(om_, tm);
      s_scale[tid] = __expf(om_ - nm);
      s_m[tid] = nm;
    }
    __syncthreads();
    const float nm0 = s_m[0], nm1 = s_m[1], nm2 = s_m[2], nm3 = s_m[3];
    const float p0 = __expf(l0 - nm0);
    const float p1 = __expf(l1 - nm1);
    const float p2 = __expf(l2 - nm2);
    const float p3 = __expf(l3 - nm3);
    s_p[0][tid] = p0; s_p[1][tid] = p1; s_p[2][tid] = p2; s_p[3][tid] = p3;
    float z0 = p0, z1 = p1, z2 = p2, z3 = p3;
    #pragma unroll
    for (int off = 32; off >= 1; off >>= 1) {
      z0 += __shfl_down(z0, off);
      z1 += __shfl_down(z1, off);
      z2 += __shfl_down(z2, off);
      z3 += __shfl_down(z3, off);
    }
    if (lane == 0) { s_red[0][wave] = z0; s_red[1][wave] = z1;
                     s_red[2][wave] = z2; s_red[3][wave] = z3; }
    acc *= s_scale[hh];
    __syncthreads();
    if (tid < NHEADS) {
      s_z[tid] = s_z[tid] * s_scale[tid] +
                 (s_red[tid][0] + s_red[tid][1] + s_red[tid][2] + s_red[tid][3]);
    }
    // PV over this tile
    const int tcnt = min(256, Nv - tbase);
    float aa0 = 0.0f, aa1 = 0.0f;
    int u2 = half;
    for (; u2 + 2 < tcnt; u2 += 4) {
      const float pA = s_p[hh][u2];
      const float pB = s_p[hh][u2 + 2];
      const int iA = s_vidx[tbase + u2];
      const int iB = s_vidx[tbase + u2 + 2];
      aa0 = fmaf(pA, vb[iA * LAT + col], aa0);
      aa1 = fmaf(pB, vb[iB * LAT + col], aa1);
    }
    for (; u2 < tcnt; u2 += 2)
      aa0 = fmaf(s_p[hh][u2], vb[s_vidx[tbase + u2] * LAT + col], aa0);
    acc += aa0 + aa1;
    __syncthreads();
  }

  if (half) s_acc[col] = acc;
  __syncthreads();
  if (!half) {
    float r = 0.0f;
    if (Nv > 0) r = (acc + s_acc[col]) / s_z[hh];
    out[((size_t)b * NQ + q) * LAT + col] = r;
  }
}

extern "C" void kernel_launch(void* const* d_in, const int* in_sizes, int n_in,
                              void* d_out, int out_size, void* d_ws, size_t ws_size,
                              hipStream_t stream) {
  const float* h_obs     = (const float*)d_in[0];
  const float* pos_obs   = (const float*)d_in[1];
  const float* pos_query = (const float*)d_in[2];
  const int*   obs_mask  = (const int*)d_in[3];
  const float* W1        = (const float*)d_in[4];
  const float* b1        = (const float*)d_in[5];
  const float* W2        = (const float*)d_in[6];
  const float* b2        = (const float*)d_in[7];
  const float* ln_g      = (const float*)d_in[8];
  const float* ln_b      = (const float*)d_in[9];
  const float* Wv        = (const float*)d_in[10];
  const float* bv        = (const float*)d_in[11];
  float* outp = (float*)d_out;
  float* v    = (float*)d_ws;

  const size_t need = V_BYTES + 2 * LAT * sizeof(float4);
  const int derived = (ws_size >= need) ? 1 : 0;
  float4* Cw = (float4*)((char*)d_ws + V_BYTES);
  float4* A4 = Cw + LAT;
  if (!derived) { Cw = (float4*)d_ws; A4 = (float4*)d_ws; }  // unused dummies

  gano_prep_kernel<<<B_ * NO, 128, 0, stream>>>(h_obs, ln_g, ln_b, Wv, bv,
                                                W1, b1, v, Cw, A4, derived);
  if (derived) {
    gano_main_kernel<true><<<B_ * NQ, 256, 0, stream>>>(
        pos_obs, pos_query, obs_mask, W1, b1, (const float4*)W2, b2, v,
        (const float4*)Cw, (const float4*)A4, outp);
  } else {
    gano_main_kernel<false><<<B_ * NQ, 256, 0, stream>>>(
        pos_obs, pos_query, obs_mask, W1, b1, (const float4*)W2, b2, v,
        (const float4*)Cw, (const float4*)A4, outp);
  }
}

// Round 3
// 39.364 us; speedup vs baseline: 1.7517x; 1.2241x over previous
//
#include <hip/hip_runtime.h>
#include <math.h>
#include <float.h>

#define B_ 2
#define NQ 1024
#define NO 1024
#define LAT 128
#define NHEADS 4
#define RADIUS_ 0.5f
#define LN_EPS_ 1e-5f
#define TILE 512
#define TILE_P (TILE + 8)

#define V_BYTES ((size_t)B_ * NO * LAT * 4)

__device__ __forceinline__ float selh(int h, float a, float b, float c, float d) {
  return h == 0 ? a : (h == 1 ? b : (h == 2 ? c : d));
}

// ---------------- prep: v = LayerNorm(h_obs) @ Wv + bv, 4 rows/block -------
__global__ __launch_bounds__(256) void gano_prep_kernel(
    const float* __restrict__ h_obs, const float* __restrict__ ln_g,
    const float* __restrict__ ln_b, const float* __restrict__ Wv,
    const float* __restrict__ bv, const float* __restrict__ W1,
    const float* __restrict__ b1, float* __restrict__ v_out,
    float4* __restrict__ Cw, float4* __restrict__ A4, int write_derived)
{
  const int tid = threadIdx.x;
  const int j = tid & 127;
  const int half = tid >> 7;          // rows {2*half, 2*half+1} of this block
  const int wave = tid >> 6;
  const int lane = tid & 63;
  const int r0 = blockIdx.x * 4 + half * 2;

  __shared__ float s_redA[2][4];
  __shared__ float s_redB[2][4];
  __shared__ __align__(16) float s_hn[4][LAT];

  const float x0 = h_obs[(size_t)r0 * LAT + j];
  const float x1 = h_obs[(size_t)(r0 + 1) * LAT + j];
  float s0 = x0, s1 = x1;
  #pragma unroll
  for (int off = 32; off >= 1; off >>= 1) {
    s0 += __shfl_down(s0, off);
    s1 += __shfl_down(s1, off);
  }
  if (lane == 0) { s_redA[0][wave] = s0; s_redA[1][wave] = s1; }
  __syncthreads();
  const float mu0 = (s_redA[0][half * 2] + s_redA[0][half * 2 + 1]) * (1.0f / LAT);
  const float mu1 = (s_redA[1][half * 2] + s_redA[1][half * 2 + 1]) * (1.0f / LAT);
  const float d0 = x0 - mu0, d1 = x1 - mu1;
  float q0 = d0 * d0, q1 = d1 * d1;
  #pragma unroll
  for (int off = 32; off >= 1; off >>= 1) {
    q0 += __shfl_down(q0, off);
    q1 += __shfl_down(q1, off);
  }
  if (lane == 0) { s_redB[0][wave] = q0; s_redB[1][wave] = q1; }
  __syncthreads();
  const float var0 = (s_redB[0][half * 2] + s_redB[0][half * 2 + 1]) * (1.0f / LAT);
  const float var1 = (s_redB[1][half * 2] + s_redB[1][half * 2 + 1]) * (1.0f / LAT);
  const float g = ln_g[j], be = ln_b[j];
  s_hn[half * 2 + 0][j] = d0 * rsqrtf(var0 + LN_EPS_) * g + be;
  s_hn[half * 2 + 1][j] = d1 * rsqrtf(var1 + LN_EPS_) * g + be;
  __syncthreads();

  float a0 = 0.0f, a1 = 0.0f;
  const float4* h0 = (const float4*)s_hn[half * 2 + 0];
  const float4* h1 = (const float4*)s_hn[half * 2 + 1];
  #pragma unroll 4
  for (int k4 = 0; k4 < LAT / 4; ++k4) {
    const float4 u0 = h0[k4];
    const float4 u1 = h1[k4];
    const float w0 = Wv[(k4 * 4 + 0) * LAT + j];
    const float w1 = Wv[(k4 * 4 + 1) * LAT + j];
    const float w2 = Wv[(k4 * 4 + 2) * LAT + j];
    const float w3 = Wv[(k4 * 4 + 3) * LAT + j];
    a0 = fmaf(u0.x, w0, a0); a0 = fmaf(u0.y, w1, a0);
    a0 = fmaf(u0.z, w2, a0); a0 = fmaf(u0.w, w3, a0);
    a1 = fmaf(u1.x, w0, a1); a1 = fmaf(u1.y, w1, a1);
    a1 = fmaf(u1.z, w2, a1); a1 = fmaf(u1.w, w3, a1);
  }
  const float bvj = bv[j];
  v_out[(size_t)(r0 + 0) * LAT + j] = a0 + bvj;
  v_out[(size_t)(r0 + 1) * LAT + j] = a1 + bvj;

  if (write_derived && blockIdx.x == 0 && tid < LAT) {
    float w[10];
    #pragma unroll
    for (int k = 0; k < 10; ++k) w[k] = W1[k * LAT + tid];
    Cw[tid] = make_float4(w[3] - w[6], w[4] - w[7], w[5] - w[8], w[9]);
    A4[tid] = make_float4(w[0] + w[6], w[1] + w[7], w[2] + w[8], b1[tid]);
  }
}

// ---------------- MLP logits for one item slot -----------------------------
template <bool DERIVED>
__device__ __forceinline__ void mlp_logits(
    int t, int Nv, const float* s_Q, const int* s_vidx, const float* s_vdist,
    const float* __restrict__ pob, const float4* __restrict__ Cw,
    const float4* __restrict__ W2v, const float* __restrict__ W1,
    float b20, float b21, float b22, float b23,
    float& l0, float& l1, float& l2, float& l3)
{
  const bool active = t < Nv;
  l0 = l1 = l2 = l3 = -FLT_MAX;
  if (!__any(active)) return;
  const int tt = active ? t : Nv - 1;
  const int idx = s_vidx[tt];
  const float dist = s_vdist[tt];
  const float ox = pob[idx * 3 + 0], oy = pob[idx * 3 + 1], oz = pob[idx * 3 + 2];
  float a0 = b20, a1 = b21, a2 = b22, a3 = b23;
  #pragma unroll 2
  for (int j4 = 0; j4 < LAT / 4; ++j4) {
    const float4 q4 = *(const float4*)&s_Q[j4 << 2];
    #pragma unroll
    for (int u = 0; u < 4; ++u) {
      const int jj = (j4 << 2) + u;
      float4 cw;
      if constexpr (DERIVED) {
        cw = Cw[jj];
      } else {
        cw = make_float4(W1[3 * LAT + jj] - W1[6 * LAT + jj],
                         W1[4 * LAT + jj] - W1[7 * LAT + jj],
                         W1[5 * LAT + jj] - W1[8 * LAT + jj],
                         W1[9 * LAT + jj]);
      }
      const float4 w2 = W2v[jj];
      const float qj = (u == 0) ? q4.x : (u == 1) ? q4.y : (u == 2) ? q4.z : q4.w;
      float gg = fmaf(cw.x, ox, qj);
      gg = fmaf(cw.y, oy, gg);
      gg = fmaf(cw.z, oz, gg);
      gg = fmaf(cw.w, dist, gg);
      gg = fmaxf(gg, 0.0f);
      a0 = fmaf(gg, w2.x, a0);
      a1 = fmaf(gg, w2.y, a1);
      a2 = fmaf(gg, w2.z, a2);
      a3 = fmaf(gg, w2.w, a3);
    }
  }
  if (active) { l0 = a0; l1 = a1; l2 = a2; l3 = a3; }
}

// ---------------- main: one block = one (b,q), 256 threads -----------------
template <bool DERIVED>
__global__ __launch_bounds__(256, 6) void gano_main_kernel(
    const float* __restrict__ pos_obs, const float* __restrict__ pos_query,
    const int* __restrict__ obs_mask,
    const float* __restrict__ W1, const float* __restrict__ b1,
    const float4* __restrict__ W2v, const float* __restrict__ b2,
    const float* __restrict__ v,
    const float4* __restrict__ Cw, const float4* __restrict__ A4,
    float* __restrict__ out)
{
  __shared__ __align__(16) float s_Q[LAT];
  __shared__ int   s_vidx[NO];
  __shared__ float s_vdist[NO];
  __shared__ float s_p[NHEADS][TILE_P];
  __shared__ int   s_cnt[16];
  __shared__ float s_red[NHEADS][4];
  __shared__ float s_zred[NHEADS][4];
  __shared__ __align__(16) float s_part[4][LAT];

  const int tid = threadIdx.x;
  const int wave = tid >> 6, lane = tid & 63;
  const int bid = blockIdx.x;
  const int b = bid >> 10, q = bid & (NQ - 1);

  const float qx = pos_query[((size_t)b * NQ + q) * 3 + 0];
  const float qy = pos_query[((size_t)b * NQ + q) * 3 + 1];
  const float qz = pos_query[((size_t)b * NQ + q) * 3 + 2];

  if (tid < LAT) {
    float a0, a1, a2, a3;
    if constexpr (DERIVED) {
      const float4 a = A4[tid];
      a0 = a.x; a1 = a.y; a2 = a.z; a3 = a.w;
    } else {
      a0 = W1[0 * LAT + tid] + W1[6 * LAT + tid];
      a1 = W1[1 * LAT + tid] + W1[7 * LAT + tid];
      a2 = W1[2 * LAT + tid] + W1[8 * LAT + tid];
      a3 = b1[tid];
    }
    s_Q[tid] = fmaf(qx, a0, fmaf(qy, a1, fmaf(qz, a2, a3)));
  }

  // ---- compaction ----
  const float* pob = pos_obs + (size_t)b * NO * 3;
  const int*   om  = obs_mask + (size_t)b * NO;
  float dists[4];
  unsigned long long bals[4];
  #pragma unroll
  for (int rd = 0; rd < 4; ++rd) {
    const int o = (rd << 8) + tid;
    const float ox = pob[o * 3 + 0], oy = pob[o * 3 + 1], oz = pob[o * 3 + 2];
    const float rx = qx - ox, ry = qy - oy, rz = qz - oz;
    const float dist = sqrtf(rx * rx + ry * ry + rz * rz);
    const int ok = (om[o] != 0) && (dist <= RADIUS_);
    const unsigned long long bal = __ballot(ok);
    if (lane == 0) s_cnt[(rd << 2) + wave] = __popcll(bal);
    bals[rd] = bal;
    dists[rd] = dist;
  }
  __syncthreads();
  int Nv = 0;
  #pragma unroll
  for (int k = 0; k < 16; ++k) Nv += s_cnt[k];
  #pragma unroll
  for (int rd = 0; rd < 4; ++rd) {
    const int slot = (rd << 2) + wave;
    int base = 0;
    for (int k = 0; k < slot; ++k) base += s_cnt[k];
    if ((bals[rd] >> lane) & 1ull) {
      const int pos = base + __popcll(bals[rd] & ((1ull << lane) - 1ull));
      s_vidx[pos] = (rd << 8) + tid;
      s_vdist[pos] = dists[rd];
    }
  }
  __syncthreads();

  // ---- per-thread PV mapping ----
  const int c5 = tid & 31;       // column group: cols 4*c5 .. 4*c5+3
  const int phase = tid >> 5;    // 0..7 item phase
  const int hh = c5 >> 3;        // head of this column group
  float ax = 0.f, ay = 0.f, az = 0.f, aw = 0.f;
  float m0 = -FLT_MAX, m1 = -FLT_MAX, m2 = -FLT_MAX, m3 = -FLT_MAX;
  float z0 = 0.f, z1 = 0.f, z2 = 0.f, z3 = 0.f;
  const float b20 = b2[0], b21 = b2[1], b22 = b2[2], b23 = b2[3];
  const float* vb = v + (size_t)b * NO * LAT;
  const float* vcol = vb + (c5 << 2);

  const int ntiles = (Nv + TILE - 1) >> 9;
  for (int tile = 0; tile < ntiles; ++tile) {
    const int tbase = tile << 9;
    float l00, l01, l02, l03, l10, l11, l12, l13;
    mlp_logits<DERIVED>(tbase + tid, Nv, s_Q, s_vidx, s_vdist, pob, Cw, W2v, W1,
                        b20, b21, b22, b23, l00, l01, l02, l03);
    mlp_logits<DERIVED>(tbase + 256 + tid, Nv, s_Q, s_vidx, s_vdist, pob, Cw, W2v, W1,
                        b20, b21, b22, b23, l10, l11, l12, l13);

    // tile max per head
    float t0 = fmaxf(l00, l10), t1 = fmaxf(l01, l11);
    float t2 = fmaxf(l02, l12), t3 = fmaxf(l03, l13);
    #pragma unroll
    for (int off = 32; off >= 1; off >>= 1) {
      t0 = fmaxf(t0, __shfl_down(t0, off));
      t1 = fmaxf(t1, __shfl_down(t1, off));
      t2 = fmaxf(t2, __shfl_down(t2, off));
      t3 = fmaxf(t3, __shfl_down(t3, off));
    }
    if (lane == 0) { s_red[0][wave] = t0; s_red[1][wave] = t1;
                     s_red[2][wave] = t2; s_red[3][wave] = t3; }
    __syncthreads();
    const float x0 = fmaxf(fmaxf(s_red[0][0], s_red[0][1]), fmaxf(s_red[0][2], s_red[0][3]));
    const float x1 = fmaxf(fmaxf(s_red[1][0], s_red[1][1]), fmaxf(s_red[1][2], s_red[1][3]));
    const float x2 = fmaxf(fmaxf(s_red[2][0], s_red[2][1]), fmaxf(s_red[2][2], s_red[2][3]));
    const float x3 = fmaxf(fmaxf(s_red[3][0], s_red[3][1]), fmaxf(s_red[3][2], s_red[3][3]));
    const float nm0 = fmaxf(m0, x0), nm1 = fmaxf(m1, x1);
    const float nm2 = fmaxf(m2, x2), nm3 = fmaxf(m3, x3);
    const float sc0 = __expf(m0 - nm0), sc1 = __expf(m1 - nm1);
    const float sc2 = __expf(m2 - nm2), sc3 = __expf(m3 - nm3);
    m0 = nm0; m1 = nm1; m2 = nm2; m3 = nm3;

    const float p00 = __expf(l00 - nm0), p01 = __expf(l01 - nm1);
    const float p02 = __expf(l02 - nm2), p03 = __expf(l03 - nm3);
    const float p10 = __expf(l10 - nm0), p11 = __expf(l11 - nm1);
    const float p12 = __expf(l12 - nm2), p13 = __expf(l13 - nm3);
    s_p[0][tid] = p00; s_p[0][256 + tid] = p10;
    s_p[1][tid] = p01; s_p[1][256 + tid] = p11;
    s_p[2][tid] = p02; s_p[2][256 + tid] = p12;
    s_p[3][tid] = p03; s_p[3][256 + tid] = p13;
    float u0 = p00 + p10, u1 = p01 + p11, u2 = p02 + p12, u3 = p03 + p13;
    #pragma unroll
    for (int off = 32; off >= 1; off >>= 1) {
      u0 += __shfl_down(u0, off);
      u1 += __shfl_down(u1, off);
      u2 += __shfl_down(u2, off);
      u3 += __shfl_down(u3, off);
    }
    if (lane == 0) { s_zred[0][wave] = u0; s_zred[1][wave] = u1;
                     s_zred[2][wave] = u2; s_zred[3][wave] = u3; }
    __syncthreads();   // also makes s_p visible
    z0 = z0 * sc0 + (s_zred[0][0] + s_zred[0][1] + s_zred[0][2] + s_zred[0][3]);
    z1 = z1 * sc1 + (s_zred[1][0] + s_zred[1][1] + s_zred[1][2] + s_zred[1][3]);
    z2 = z2 * sc2 + (s_zred[2][0] + s_zred[2][1] + s_zred[2][2] + s_zred[2][3]);
    z3 = z3 * sc3 + (s_zred[3][0] + s_zred[3][1] + s_zred[3][2] + s_zred[3][3]);
    const float scme = selh(hh, sc0, sc1, sc2, sc3);
    ax *= scme; ay *= scme; az *= scme; aw *= scme;

    // PV over this tile: thread covers cols [4*c5,4*c5+4), items phase::8
    const int tcnt = min(TILE, Nv - tbase);
    int it = phase;
    float bx = 0.f, by = 0.f, bz = 0.f, bw = 0.f;
    for (; it + 8 < tcnt; it += 16) {
      const float pA = s_p[hh][it];
      const float pB = s_p[hh][it + 8];
      const int iA = s_vidx[tbase + it];
      const int iB = s_vidx[tbase + it + 8];
      const float4 vA = *(const float4*)(vcol + (size_t)iA * LAT);
      const float4 vB = *(const float4*)(vcol + (size_t)iB * LAT);
      ax = fmaf(pA, vA.x, ax); ay = fmaf(pA, vA.y, ay);
      az = fmaf(pA, vA.z, az); aw = fmaf(pA, vA.w, aw);
      bx = fmaf(pB, vB.x, bx); by = fmaf(pB, vB.y, by);
      bz = fmaf(pB, vB.z, bz); bw = fmaf(pB, vB.w, bw);
    }
    if (it < tcnt) {
      const float pA = s_p[hh][it];
      const int iA = s_vidx[tbase + it];
      const float4 vA = *(const float4*)(vcol + (size_t)iA * LAT);
      ax = fmaf(pA, vA.x, ax); ay = fmaf(pA, vA.y, ay);
      az = fmaf(pA, vA.z, az); aw = fmaf(pA, vA.w, aw);
    }
    ax += bx; ay += by; az += bz; aw += bw;
    if (tile + 1 < ntiles) __syncthreads();  // protect s_p/s_red reuse
  }

  // ---- final reduce: combine the two phases in each wave, then cross-wave --
  ax += __shfl_down(ax, 32);
  ay += __shfl_down(ay, 32);
  az += __shfl_down(az, 32);
  aw += __shfl_down(aw, 32);
  if (lane < 32) {
    *(float4*)&s_part[wave][lane << 2] = make_float4(ax, ay, az, aw);
  }
  __syncthreads();
  if (tid < LAT) {
    const float r4 = s_part[0][tid] + s_part[1][tid] + s_part[2][tid] + s_part[3][tid];
    const int h = tid >> 5;
    const float zz = selh(h, z0, z1, z2, z3);
    const float r = (Nv > 0) ? (r4 / zz) : 0.0f;
    out[((size_t)b * NQ + q) * LAT + tid] = r;
  }
}

extern "C" void kernel_launch(void* const* d_in, const int* in_sizes, int n_in,
                              void* d_out, int out_size, void* d_ws, size_t ws_size,
                              hipStream_t stream) {
  const float* h_obs     = (const float*)d_in[0];
  const float* pos_obs   = (const float*)d_in[1];
  const float* pos_query = (const float*)d_in[2];
  const int*   obs_mask  = (const int*)d_in[3];
  const float* W1        = (const float*)d_in[4];
  const float* b1        = (const float*)d_in[5];
  const float* W2        = (const float*)d_in[6];
  const float* b2        = (const float*)d_in[7];
  const float* ln_g      = (const float*)d_in[8];
  const float* ln_b      = (const float*)d_in[9];
  const float* Wv        = (const float*)d_in[10];
  const float* bv        = (const float*)d_in[11];
  float* outp = (float*)d_out;
  float* v    = (float*)d_ws;

  const size_t need = V_BYTES + 2 * LAT * sizeof(float4);
  const int derived = (ws_size >= need) ? 1 : 0;
  float4* Cw = (float4*)((char*)d_ws + V_BYTES);
  float4* A4 = Cw + LAT;
  if (!derived) { Cw = (float4*)d_ws; A4 = (float4*)d_ws; }

  gano_prep_kernel<<<(B_ * NO) / 4, 256, 0, stream>>>(h_obs, ln_g, ln_b, Wv, bv,
                                                      W1, b1, v, Cw, A4, derived);
  if (derived) {
    gano_main_kernel<true><<<B_ * NQ, 256, 0, stream>>>(
        pos_obs, pos_query, obs_mask, W1, b1, (const float4*)W2, b2, v,
        (const float4*)Cw, (const float4*)A4, outp);
  } else {
    gano_main_kernel<false><<<B_ * NQ, 256, 0, stream>>>(
        pos_obs, pos_query, obs_mask, W1, b1, (const float4*)W2, b2, v,
        (const float4*)Cw, (const float4*)A4, outp);
  }
}